// Round 1
// baseline (167.445 us; speedup 1.0000x reference)
//
#include <hip/hip_runtime.h>
#include <math.h>

#define C_DIMK 2048
#define I_DIMK 4096

// One block per output row r. 4 waves/block; wave w computes the GEMV row
// for gate w (f, i, c, o). Each wave: 64 lanes x float4 x 16 iters = 4096
// elements. Wave-reduce via shfl, combine 4 partials in LDS, thread 0 does
// the gating math and writes c_new/h_new.
__global__ __launch_bounds__(256, 4) void lstm_fused_kernel(
    const float* __restrict__ h, const float* __restrict__ c,
    const float* __restrict__ x,
    const float* __restrict__ wf, const float* __restrict__ bf,
    const float* __restrict__ wi, const float* __restrict__ bi,
    const float* __restrict__ wo, const float* __restrict__ bo,
    const float* __restrict__ wc, const float* __restrict__ bc,
    float* __restrict__ out)
{
    const int r    = blockIdx.x;
    const int wave = threadIdx.x >> 6;   // 0..3
    const int lane = threadIdx.x & 63;

    // Gate order must match reference g-layout: [f, i, c, o]
    const float* W;
    switch (wave) {
        case 0:  W = wf; break;
        case 1:  W = wi; break;
        case 2:  W = wc; break;
        default: W = wo; break;
    }
    const float4* Wrow = reinterpret_cast<const float4*>(W + (size_t)r * I_DIMK);

    float sum = 0.0f;
    #pragma unroll
    for (int it = 0; it < 16; ++it) {
        const int e4   = it * 64 + lane;   // float4 index within the row
        const int base = e4 * 4;           // element index in i = cat(x, h)
        float4 wv = Wrow[e4];
        // base is wave-uniformly < 2048 for it < 8 (each iter spans 256
        // contiguous elements), so this branch never diverges within a wave.
        const float* src = (base < C_DIMK) ? (x + base) : (h + (base - C_DIMK));
        float4 xv = *reinterpret_cast<const float4*>(src);
        sum = fmaf(wv.x, xv.x, sum);
        sum = fmaf(wv.y, xv.y, sum);
        sum = fmaf(wv.z, xv.z, sum);
        sum = fmaf(wv.w, xv.w, sum);
    }

    // Wave64 reduction
    #pragma unroll
    for (int off = 32; off > 0; off >>= 1)
        sum += __shfl_down(sum, off, 64);

    __shared__ float partial[4];
    if (lane == 0) partial[wave] = sum;
    __syncthreads();

    if (threadIdx.x == 0) {
        const float gf = partial[0] + bf[r];
        const float gi = partial[1] + bi[r];
        const float gc = partial[2] + bc[r];
        const float go = partial[3] + bo[r];
        const float ff = 1.0f / (1.0f + __expf(-gf));
        const float ig = 1.0f / (1.0f + __expf(-gi));
        const float cc = tanhf(gc);
        const float oo = 1.0f / (1.0f + __expf(-go));
        const float cn = fmaf(ff, c[r], ig * cc);
        const float hn = tanhf(cn) * oo;
        out[r]          = cn;   // c_new
        out[C_DIMK + r] = hn;   // h_new
    }
}

extern "C" void kernel_launch(void* const* d_in, const int* in_sizes, int n_in,
                              void* d_out, int out_size, void* d_ws, size_t ws_size,
                              hipStream_t stream) {
    // setup_inputs() order: h, c, x, wf, bf, wi, bi, wo, bo, wc, bc (all fp32)
    const float* h  = (const float*)d_in[0];
    const float* c  = (const float*)d_in[1];
    const float* x  = (const float*)d_in[2];
    const float* wf = (const float*)d_in[3];
    const float* bf = (const float*)d_in[4];
    const float* wi = (const float*)d_in[5];
    const float* bi = (const float*)d_in[6];
    const float* wo = (const float*)d_in[7];
    const float* bo = (const float*)d_in[8];
    const float* wc = (const float*)d_in[9];
    const float* bc = (const float*)d_in[10];
    float* out = (float*)d_out;

    lstm_fused_kernel<<<C_DIMK, 256, 0, stream>>>(
        h, c, x, wf, bf, wi, bi, wo, bo, wc, bc, out);
}

// Round 2
// 161.850 us; speedup vs baseline: 1.0346x; 1.0346x over previous
//
#include <hip/hip_runtime.h>
#include <math.h>

#define C_DIMK 2048
#define I_DIMK 4096
#define NV4    (I_DIMK / 4)   // float4 chunks per weight row

// One block per output row r. 4 waves/block; wave w owns gate w (f,i,c,o).
// Staging: block cooperatively copies i = cat(x,h) (16 KB) into LDS once.
// Each wave issues ALL 16 float4 weight loads back-to-back into registers
// (16 KB in flight per wave -> deep vmcnt pipeline), then consumes them
// against LDS x with 4 rotating accumulators (no 64-deep dependent chain).
__global__ __launch_bounds__(256, 4) void lstm_fused_kernel(
    const float* __restrict__ h, const float* __restrict__ c,
    const float* __restrict__ x,
    const float* __restrict__ wf, const float* __restrict__ bf,
    const float* __restrict__ wi, const float* __restrict__ bi,
    const float* __restrict__ wo, const float* __restrict__ bo,
    const float* __restrict__ wc, const float* __restrict__ bc,
    float* __restrict__ out)
{
    __shared__ float4 xs[NV4];          // 16 KB: cat(x, h)
    const int r    = blockIdx.x;
    const int t    = threadIdx.x;
    const int wave = t >> 6;            // 0..3 -> gate f,i,c,o
    const int lane = t & 63;

    // Gate order matches reference g-layout: [f, i, c, o]
    const float* W = (wave == 0) ? wf : (wave == 1) ? wi : (wave == 2) ? wc : wo;
    const float4* Wrow = reinterpret_cast<const float4*>(W) + (size_t)r * NV4;

    // Issue all 16 weight loads first — 16 KB in flight per wave.
    float4 w[16];
    #pragma unroll
    for (int j = 0; j < 16; ++j) w[j] = Wrow[j * 64 + lane];

    // Stage cat(x,h) into LDS (uniform branch per j: j<2 -> x, j>=2 -> h).
    const float4* X4 = reinterpret_cast<const float4*>(x);
    const float4* H4 = reinterpret_cast<const float4*>(h);
    #pragma unroll
    for (int j = 0; j < 4; ++j) {
        const int idx = j * 256 + t;    // 0..1023
        xs[idx] = (idx < 512) ? X4[idx] : H4[idx - 512];
    }
    __syncthreads();

    // Consume: LDS x vs register weights, 4 rotating accumulators.
    float a0 = 0.f, a1 = 0.f, a2 = 0.f, a3 = 0.f;
    #pragma unroll
    for (int j = 0; j < 16; ++j) {
        const float4 xv = xs[j * 64 + lane];
        const float4 wv = w[j];
        float d = wv.x * xv.x;
        d = fmaf(wv.y, xv.y, d);
        d = fmaf(wv.z, xv.z, d);
        d = fmaf(wv.w, xv.w, d);
        switch (j & 3) {
            case 0: a0 += d; break;
            case 1: a1 += d; break;
            case 2: a2 += d; break;
            default: a3 += d; break;
        }
    }
    float sum = (a0 + a1) + (a2 + a3);

    // Wave64 reduction
    #pragma unroll
    for (int off = 32; off > 0; off >>= 1)
        sum += __shfl_down(sum, off, 64);

    __shared__ float partial[4];
    if (lane == 0) partial[wave] = sum;
    __syncthreads();

    if (t == 0) {
        const float gf = partial[0] + bf[r];
        const float gi = partial[1] + bi[r];
        const float gc = partial[2] + bc[r];
        const float go = partial[3] + bo[r];
        const float ff = 1.0f / (1.0f + __expf(-gf));
        const float ig = 1.0f / (1.0f + __expf(-gi));
        const float cc = tanhf(gc);
        const float oo = 1.0f / (1.0f + __expf(-go));
        const float cn = fmaf(ff, c[r], ig * cc);
        const float hn = tanhf(cn) * oo;
        out[r]          = cn;   // c_new
        out[C_DIMK + r] = hn;   // h_new
    }
}

extern "C" void kernel_launch(void* const* d_in, const int* in_sizes, int n_in,
                              void* d_out, int out_size, void* d_ws, size_t ws_size,
                              hipStream_t stream) {
    // setup_inputs() order: h, c, x, wf, bf, wi, bi, wo, bo, wc, bc (all fp32)
    const float* h  = (const float*)d_in[0];
    const float* c  = (const float*)d_in[1];
    const float* x  = (const float*)d_in[2];
    const float* wf = (const float*)d_in[3];
    const float* bf = (const float*)d_in[4];
    const float* wi = (const float*)d_in[5];
    const float* bi = (const float*)d_in[6];
    const float* wo = (const float*)d_in[7];
    const float* bo = (const float*)d_in[8];
    const float* wc = (const float*)d_in[9];
    const float* bc = (const float*)d_in[10];
    float* out = (float*)d_out;

    lstm_fused_kernel<<<C_DIMK, 256, 0, stream>>>(
        h, c, x, wf, bf, wi, bi, wo, bo, wc, bc, out);
}